// Round 12
// baseline (352.408 us; speedup 1.0000x reference)
//
#include <hip/hip_runtime.h>
#include <math.h>

// GaussianKDE: out[b,l] = sum_n w[n] * exp(-||x[b,l]-data[n]||^2 / SIGMA)
// B=2, L=65536, D=2, N=16384, SIGMA=3.0
//
// Gridded fast Gauss transform on a h=1/3 lattice (128^2, span +-21.33),
// bicubic interp both sides, conv radius 18 cells (= 6 units).
//
// R11: ONE dispatch. Each block redundantly builds the ENTIRE grid in its
// own LDS: zero -> deposit all N points (LDS atomics, ~1.7us) -> conv-x
// into regs (float4 windows, g(k) const-folded) -> rewrite same LDS buffer
// as TRANSPOSED BT[x][24+y] with zeroed pads -> gather its own 512
// locations (contiguous y-window, sliding combined weight). No inter-block
// dependency: no 2nd dispatch, no grid.sync, no cross-call state, d_ws
// unused. LDS = max(128*164, 128*168) floats = 86KB -> 1 block/CU.
// Work/block ~7us, 256 blocks on 256 CUs. Predict ~10us overhead + ~7us.

#define GN     128
#define CR     18
#define ASTR   (GN + 2 * CR)      // 164: deposit row stride (4-aligned)
#define BPADL  24
#define BSTR   (GN + BPADL + 16)  // 168: BT row stride (cols [-24,144))
#define LDSF   (GN * BSTR)        // 21504 floats = 86016 B (> GN*ASTR=20992)
#define GORG   (-21.3333333f)
#define GINVH  3.0f
#define H2C2   0.05343315f        // h^2/(3*ln2), h=1/3: g(k)=2^(-k^2*H2C2)
#define NTHR   512

__device__ __forceinline__ float fast_exp2(float x) {
#if __has_builtin(__builtin_amdgcn_exp2f)
    return __builtin_amdgcn_exp2f(x);
#else
    float r;
    asm volatile("v_exp_f32 %0, %1" : "=v"(r) : "v"(x));
    return r;
#endif
}

// Cubic Lagrange weights for nodes {-1,0,1,2} at fractional t in [0,1).
__device__ __forceinline__ void cubw(float t, float w[4]) {
    float t2 = t * t;
    w[0] = -t * (t - 1.0f) * (t - 2.0f) * (1.0f / 6.0f);
    w[1] = (t2 - 1.0f) * (t - 2.0f) * 0.5f;
    w[2] = -t * (t + 1.0f) * (t - 2.0f) * 0.5f;
    w[3] = t * (t2 - 1.0f) * (1.0f / 6.0f);
}

__global__ __launch_bounds__(NTHR) void kde_one(const float2* __restrict__ x,
                                                const float2* __restrict__ data,
                                                const float* __restrict__ w,
                                                float* __restrict__ out, int N) {
    __shared__ float L[LDSF];
    const int tid = threadIdx.x;

    // ---- P0: zero LDS ----
#pragma unroll
    for (int i = tid; i < LDSF / 4; i += NTHR) {
        ((float4*)L)[i] = make_float4(0.f, 0.f, 0.f, 0.f);
    }
    __syncthreads();

    // ---- P1: deposit all N points (A[j][18+i], stride 164) ----
#pragma unroll 4
    for (int n = tid; n < N; n += NTHR) {
        float2 d = data[n];
        float wn = w[n];
        float u = (d.x - GORG) * GINVH;
        float v = (d.y - GORG) * GINVH;
        float fu = floorf(u), fv = floorf(v);
        int i0 = (int)fu - 1, j0 = (int)fv - 1;
        i0 = min(max(i0, 0), GN - 4);   // safety; |d| < ~18
        j0 = min(max(j0, 0), GN - 4);
        float tu = u - fu, tv = v - fv;
        float wx[4], wy[4];
        cubw(tu, wx);
        cubw(tv, wy);
        int a0 = j0 * ASTR + CR + i0;
#pragma unroll
        for (int dy = 0; dy < 4; ++dy) {
            float wwy = wn * wy[dy];
            atomicAdd(&L[a0 + dy * ASTR + 0], wwy * wx[0]);
            atomicAdd(&L[a0 + dy * ASTR + 1], wwy * wx[1]);
            atomicAdd(&L[a0 + dy * ASTR + 2], wwy * wx[2]);
            atomicAdd(&L[a0 + dy * ASTR + 3], wwy * wx[3]);
        }
    }
    __syncthreads();

    // ---- P2: conv-x into registers (each thread: 8 groups of 4 cells) ----
    float gk[CR + 1];
#pragma unroll
    for (int k = 0; k <= CR; ++k) gk[k] = exp2f(-(float)(k * k) * H2C2);  // const-folds

    float res[32];
#pragma unroll
    for (int s = 0; s < 8; ++s) {
        const int c = tid * 4 + s * (NTHR * 4);   // cell index, i = c&127 ≡ 0 mod 4
        const int j = c >> 7, i = c & (GN - 1);
        float win[40];                            // A cols [i, i+40)
        const float4* wp = (const float4*)&L[j * ASTR + i];  // 164,i ≡ 0 mod 4
#pragma unroll
        for (int t = 0; t < 10; ++t) {
            float4 q = wp[t];
            win[4 * t + 0] = q.x; win[4 * t + 1] = q.y;
            win[4 * t + 2] = q.z; win[4 * t + 3] = q.w;
        }
#pragma unroll
        for (int cc = 0; cc < 4; ++cc) {
            float acc = 0.0f;
#pragma unroll
            for (int k = -CR; k <= CR; ++k) {
                acc = fmaf(win[CR + cc + k], gk[k < 0 ? -k : k], acc);
            }
            res[s * 4 + cc] = acc;
        }
    }
    __syncthreads();   // all reads of A complete before overwrite

    // ---- P3: write transposed BT[i][24+j] (stride 168) + zero pads ----
#pragma unroll
    for (int s = 0; s < 8; ++s) {
        const int c = tid * 4 + s * (NTHR * 4);
        const int j = c >> 7, i = c & (GN - 1);
        L[(i + 0) * BSTR + BPADL + j] = res[s * 4 + 0];
        L[(i + 1) * BSTR + BPADL + j] = res[s * 4 + 1];
        L[(i + 2) * BSTR + BPADL + j] = res[s * 4 + 2];
        L[(i + 3) * BSTR + BPADL + j] = res[s * 4 + 3];
    }
    // pads: rows 0..127, cols [0,24) and [152,168)
    for (int p = tid; p < GN * (BPADL + 16); p += NTHR) {
        const int row = p / 40, c = p % 40;
        const int col = (c < BPADL) ? c : (c + GN);
        L[row * BSTR + col] = 0.0f;
    }
    __syncthreads();

    // ---- P4: gather own 512 locations ----
    const int loc = blockIdx.x * NTHR + tid;
    float2 xi = x[loc];
    float u = (xi.x - GORG) * GINVH;
    float v = (xi.y - GORG) * GINVH;
    float fu = floorf(u), fv = floorf(v);
    float tu = u - fu, tv = v - fv;
    int i0 = (int)fu - 1, j0 = (int)fv - 1;
    i0 = min(max(i0, 0), GN - 4);
    j0 = min(max(j0, 0), GN - 4);
    float wx[4], wy[4];
    cubw(tu, wx);
    cubw(tv, wy);

    const int js = (j0 - (CR + 3)) & ~3;          // 4-aligned, >= -24
    float winc[44];
    const float4* r0 = (const float4*)&L[(i0 + 0) * BSTR + BPADL + js];
    const float4* r1 = (const float4*)&L[(i0 + 1) * BSTR + BPADL + js];
    const float4* r2 = (const float4*)&L[(i0 + 2) * BSTR + BPADL + js];
    const float4* r3 = (const float4*)&L[(i0 + 3) * BSTR + BPADL + js];
#pragma unroll
    for (int t = 0; t < 11; ++t) {
        float4 a = r0[t], b = r1[t], c = r2[t], d = r3[t];
        winc[4 * t + 0] = fmaf(wx[0], a.x, fmaf(wx[1], b.x, fmaf(wx[2], c.x, wx[3] * d.x)));
        winc[4 * t + 1] = fmaf(wx[0], a.y, fmaf(wx[1], b.y, fmaf(wx[2], c.y, wx[3] * d.y)));
        winc[4 * t + 2] = fmaf(wx[0], a.z, fmaf(wx[1], b.z, fmaf(wx[2], c.z, wx[3] * d.z)));
        winc[4 * t + 3] = fmaf(wx[0], a.w, fmaf(wx[1], b.w, fmaf(wx[2], c.w, wx[3] * d.w)));
    }

    float mmf = (float)(js - j0);
    float gm1 = fast_exp2(-(mmf - 1.f) * (mmf - 1.f) * H2C2);
    float gm2 = fast_exp2(-(mmf - 2.f) * (mmf - 2.f) * H2C2);
    float gm3 = fast_exp2(-(mmf - 3.f) * (mmf - 3.f) * H2C2);
    float acc = 0.0f;
#pragma unroll
    for (int tt = 0; tt < 44; ++tt) {
        float m = mmf + (float)tt;
        float gm = fast_exp2(-m * m * H2C2);
        float W = fmaf(wy[0], gm, fmaf(wy[1], gm1, fmaf(wy[2], gm2, wy[3] * gm3)));
        acc = fmaf(W, winc[tt], acc);
        gm3 = gm2; gm2 = gm1; gm1 = gm;
    }
    out[loc] = acc;
}

// ------------------- fallback: R10-verified 2-kernel path -------------------
__global__ __launch_bounds__(512) void kde_k1(const float2* __restrict__ data,
                                              const float* __restrict__ w,
                                              float* __restrict__ BTg, int N) {
    __shared__ float Arow[ASTR];
    const int j = blockIdx.x;
    const int tid = threadIdx.x;
    for (int i = tid; i < ASTR; i += 512) Arow[i] = 0.0f;
    __syncthreads();
#pragma unroll 8
    for (int n = tid; n < N; n += 512) {
        float2 d = data[n];
        float v  = (d.y - GORG) * GINVH;
        float fv = floorf(v);
        int j0 = (int)fv - 1;
        j0 = min(max(j0, 0), GN - 4);
        int m = j - j0;
        if (m >= 0 && m <= 3) {
            float wn = w[n];
            float tv = v - fv;
            float wy[4];
            cubw(tv, wy);
            float wym = (m == 0) ? wy[0] : (m == 1) ? wy[1] : (m == 2) ? wy[2] : wy[3];
            float u  = (d.x - GORG) * GINVH;
            float fu = floorf(u);
            int i0 = (int)fu - 1;
            i0 = min(max(i0, 0), GN - 4);
            float tu = u - fu;
            float wx[4];
            cubw(tu, wx);
            float ww = wn * wym;
            atomicAdd(&Arow[CR + i0 + 0], ww * wx[0]);
            atomicAdd(&Arow[CR + i0 + 1], ww * wx[1]);
            atomicAdd(&Arow[CR + i0 + 2], ww * wx[2]);
            atomicAdd(&Arow[CR + i0 + 3], ww * wx[3]);
        }
    }
    __syncthreads();
    if (tid < GN) {
        float s = 0.0f;
#pragma unroll
        for (int k = -CR; k <= CR; ++k) {
            s = fmaf(Arow[CR + tid + k], fast_exp2(-(float)(k * k) * H2C2), s);
        }
        BTg[tid * BSTR + BPADL + j] = s;
    }
    if (tid < BPADL + 16) {
        int col = (tid < BPADL) ? tid : (tid + GN);
        BTg[j * BSTR + col] = 0.0f;
    }
}

__global__ __launch_bounds__(512) void kde_k2(const float2* __restrict__ x,
                                              const float* __restrict__ BTg,
                                              float* __restrict__ out) {
    __shared__ float BT[LDSF];
#pragma unroll
    for (int i = threadIdx.x; i < LDSF / 4; i += 512) {
        ((float4*)BT)[i] = ((const float4*)BTg)[i];
    }
    __syncthreads();
    const int loc = blockIdx.x * 512 + threadIdx.x;
    float2 xi = x[loc];
    float u = (xi.x - GORG) * GINVH;
    float v = (xi.y - GORG) * GINVH;
    float fu = floorf(u), fv = floorf(v);
    float tu = u - fu, tv = v - fv;
    int i0 = (int)fu - 1, j0 = (int)fv - 1;
    i0 = min(max(i0, 0), GN - 4);
    j0 = min(max(j0, 0), GN - 4);
    float wx[4], wy[4];
    cubw(tu, wx);
    cubw(tv, wy);
    const int js = (j0 - (CR + 3)) & ~3;
    float winc[44];
    const float4* r0 = (const float4*)&BT[(i0 + 0) * BSTR + BPADL + js];
    const float4* r1 = (const float4*)&BT[(i0 + 1) * BSTR + BPADL + js];
    const float4* r2 = (const float4*)&BT[(i0 + 2) * BSTR + BPADL + js];
    const float4* r3 = (const float4*)&BT[(i0 + 3) * BSTR + BPADL + js];
#pragma unroll
    for (int t = 0; t < 11; ++t) {
        float4 a = r0[t], b = r1[t], c = r2[t], d = r3[t];
        winc[4 * t + 0] = fmaf(wx[0], a.x, fmaf(wx[1], b.x, fmaf(wx[2], c.x, wx[3] * d.x)));
        winc[4 * t + 1] = fmaf(wx[0], a.y, fmaf(wx[1], b.y, fmaf(wx[2], c.y, wx[3] * d.y)));
        winc[4 * t + 2] = fmaf(wx[0], a.z, fmaf(wx[1], b.z, fmaf(wx[2], c.z, wx[3] * d.z)));
        winc[4 * t + 3] = fmaf(wx[0], a.w, fmaf(wx[1], b.w, fmaf(wx[2], c.w, wx[3] * d.w)));
    }
    float mmf = (float)(js - j0);
    float gm1 = fast_exp2(-(mmf - 1.f) * (mmf - 1.f) * H2C2);
    float gm2 = fast_exp2(-(mmf - 2.f) * (mmf - 2.f) * H2C2);
    float gm3 = fast_exp2(-(mmf - 3.f) * (mmf - 3.f) * H2C2);
    float acc = 0.0f;
#pragma unroll
    for (int tt = 0; tt < 44; ++tt) {
        float m = mmf + (float)tt;
        float gm = fast_exp2(-m * m * H2C2);
        float W = fmaf(wy[0], gm, fmaf(wy[1], gm1, fmaf(wy[2], gm2, wy[3] * gm3)));
        acc = fmaf(W, winc[tt], acc);
        gm3 = gm2; gm2 = gm1; gm1 = gm;
    }
    out[loc] = acc;
}
// -----------------------------------------------------------------------------

extern "C" void kernel_launch(void* const* d_in, const int* in_sizes, int n_in,
                              void* d_out, int out_size, void* d_ws, size_t ws_size,
                              hipStream_t stream) {
    const float2* x      = (const float2*)d_in[0];  // (B*L, 2) f32
    const float2* data   = (const float2*)d_in[1];  // (N, 2)   f32
    const float* weights = (const float*)d_in[2];   // (N,)     f32
    float* out           = (float*)d_out;           // (B*L,)   f32

    const int N     = in_sizes[2];        // 16384
    const int n_loc = in_sizes[0] / 2;    // 131072

    if ((n_loc % NTHR) == 0) {
        kde_one<<<n_loc / NTHR, NTHR, 0, stream>>>(x, data, weights, out, N);
    } else {
        // fallback: R10-verified 2-kernel path
        float* BTg = (float*)d_ws;                   // LDSF floats = 86KB
        kde_k1<<<GN, 512, 0, stream>>>(data, weights, BTg, N);
        kde_k2<<<n_loc / 512, 512, 0, stream>>>(x, BTg, out);
    }
}